// Round 10
// baseline (132.384 us; speedup 1.0000x reference)
//
#include <hip/hip_runtime.h>
#include <hip/hip_bf16.h>

#define NPART 8192
#define NCT 4
#define CDIM 20
#define NCELL (CDIM * CDIM * CDIM)          // 8000 cells, cell edge = cutoff = 2.0
#define CAP 12                              // max particles/cell (lambda~1.02)
#define POISON_U 0xAAAAAAAAu
#define NBLOCKS 1024
#define TPB 256
#define PPB (NPART / NBLOCKS)               // 8 particles decoded per block

// ws layout (bytes):
//   0        float acc64[64]          poison-biased partial sums (proven finalize)
//   256      uint  cnt                finalize counter (poisoned)
//   260      uint  bar                grid-barrier counter (poisoned)
//   512      uint  count[8000]        poison-biased bin counters (device atomics)
//   32768    u64   crec64[8000*12*2]  cell records (x,y | z,rad) — agent-scope st/ld
//   1568768  uint  cmeta[8000*12]     (i<<2)|spec — agent-scope st/ld
// total ~2 MB of 256 MiB ws

__device__ __forceinline__ float loadf(const void* p, int idx, bool bf) {
    if (bf) {
        unsigned int u = ((const unsigned short*)p)[idx];
        return __uint_as_float(u << 16);
    }
    return ((const float*)p)[idx];
}

__device__ __forceinline__ int spec_of(const void* ct, int i, bool bf) {
    int s = -1;
#pragma unroll
    for (int c = 0; c < NCT; ++c)
        if (loadf(ct, i * NCT + c, bf) > 0.5f) s = c;
    return s;
}

__device__ __forceinline__ int cell_coord(float v) {
    return min(CDIM - 1, max(0, (int)(v * 0.5f)));
}

__global__ __launch_bounds__(TPB, 8)        // 8 waves/SIMD min -> all 1024 blocks co-resident
void morse_fused_kernel(const void* __restrict__ eps,
                        const void* __restrict__ alp,
                        const void* __restrict__ ct,
                        const void* __restrict__ rad,
                        const void* __restrict__ pos,
                        float* __restrict__ acc64,
                        unsigned int* __restrict__ cnt,
                        unsigned int* __restrict__ bar,
                        unsigned int* __restrict__ count,
                        unsigned long long* __restrict__ crec64,
                        unsigned int* __restrict__ cmeta,
                        void* __restrict__ out)
{
    __shared__ float ls[32];
    __shared__ float red[TPB / 64];

    const int t = threadIdx.x;
    const int b = blockIdx.x;

    // dtype detection (wave-uniform): fp32 one-hot words always have low16 == 0
    unsigned int wdet = ((const unsigned int*)ct)[t & 63];
    const bool bf = (__ballot((wdet & 0xFFFFu) != 0) != 0ull);

    // species tables (per block, into LDS): symmetrize + sigmoid*vmax + vmin
    if (t < 16) {
        int a = t >> 2, c = t & 3;
        float me = (a == c) ? loadf(eps, a * NCT + a, bf)
                            : 0.5f * (loadf(eps, a * NCT + c, bf) + loadf(eps, c * NCT + a, bf));
        float ma = (a == c) ? loadf(alp, a * NCT + a, bf)
                            : 0.5f * (loadf(alp, a * NCT + c, bf) + loadf(alp, c * NCT + a, bf));
        ls[t]      = 5.0f / (1.0f + __expf(-me)) + 1.0f;   // EPS range
        ls[16 + t] = 3.0f / (1.0f + __expf(-ma)) + 1.0f;   // ALPHA range
    }

    // ---- Phase 1: decode 8 particles per block into cell bins ----
    if (t < PPB) {
        int i = b * PPB + t;
        float4 p;
        p.x = loadf(pos, i * 3 + 0, bf);
        p.y = loadf(pos, i * 3 + 1, bf);
        p.z = loadf(pos, i * 3 + 2, bf);
        p.w = loadf(rad, i, bf);
        int s = spec_of(ct, i, bf);
        if (s >= 0) {
            int c = (cell_coord(p.z) * CDIM + cell_coord(p.y)) * CDIM + cell_coord(p.x);
            unsigned int slot = atomicAdd(&count[c], 1u) - POISON_U;  // poison-based counters
            if (slot < CAP) {
                int idx = c * CAP + (int)slot;
                unsigned long long lo = ((unsigned long long)__float_as_uint(p.y) << 32)
                                        | __float_as_uint(p.x);
                unsigned long long hi = ((unsigned long long)__float_as_uint(p.w) << 32)
                                        | __float_as_uint(p.z);
                // agent-scope stores: write through to the device-coherent point
                __hip_atomic_store(&crec64[idx * 2 + 0], lo, __ATOMIC_RELAXED, __HIP_MEMORY_SCOPE_AGENT);
                __hip_atomic_store(&crec64[idx * 2 + 1], hi, __ATOMIC_RELAXED, __HIP_MEMORY_SCOPE_AGENT);
                __hip_atomic_store(&cmeta[idx], (unsigned int)((i << 2) | s), __ATOMIC_RELAXED, __HIP_MEMORY_SCOPE_AGENT);
            }
        }
        __threadfence();      // drain + make the stores device-visible before barrier arrive
    }
    __syncthreads();

    // ---- Grid barrier (all 1024 blocks co-resident by capacity) ----
    if (t == 0) {
        __hip_atomic_fetch_add(bar, 1u, __ATOMIC_ACQ_REL, __HIP_MEMORY_SCOPE_AGENT);
        int spins = 0;
        while (__hip_atomic_load(bar, __ATOMIC_ACQUIRE, __HIP_MEMORY_SCOPE_AGENT) - POISON_U
               < (unsigned int)NBLOCKS) {
            __builtin_amdgcn_s_sleep(4);
            if (++spins > (1 << 22)) break;   // bail-out: fail visibly instead of hanging
        }
    }
    __syncthreads();

    // ---- Phase 2: pair energy; thread = (particle i, neighbor-cell k in 0..31) ----
    constexpr float RC2 = 4.0f;             // R_CUTOFF^2
    constexpr float RO2 = 1.7f * 1.7f;      // R_ONSET^2
    constexpr float C1  = RC2 - 3.0f * RO2;
    const float INV_D = 1.0f / ((RC2 - RO2) * (RC2 - RO2) * (RC2 - RO2));

    const int gtid = b * TPB + t;
    const int i = gtid >> 5;
    const int k = gtid & 31;

    // re-decode own i (lanes sharing i broadcast from L1; no cross-block dependency)
    float4 pi;
    pi.x = loadf(pos, i * 3 + 0, bf);
    pi.y = loadf(pos, i * 3 + 1, bf);
    pi.z = loadf(pos, i * 3 + 2, bf);
    pi.w = loadf(rad, i, bf);
    const int si = spec_of(ct, i, bf);

    float acc = 0.0f;
    if (k < 27 && si >= 0) {
        const int xx = cell_coord(pi.x) + (k % 3) - 1;
        const int yy = cell_coord(pi.y) + ((k / 3) % 3) - 1;
        const int zz = cell_coord(pi.z) + (k / 9) - 1;
        if (xx >= 0 && xx < CDIM && yy >= 0 && yy < CDIM && zz >= 0 && zz < CDIM) {
            const int c = (zz * CDIM + yy) * CDIM + xx;
            // agent-scope loads bypass non-coherent L1/L2 -> see decode's stores
            unsigned int n = __hip_atomic_load(&count[c], __ATOMIC_RELAXED, __HIP_MEMORY_SCOPE_AGENT)
                             - POISON_U;
            n = (n > CAP) ? CAP : n;
            for (unsigned int ss = 0; ss < n; ++ss) {
                int idx = c * CAP + (int)ss;
                unsigned long long lo = __hip_atomic_load(&crec64[idx * 2 + 0], __ATOMIC_RELAXED, __HIP_MEMORY_SCOPE_AGENT);
                unsigned long long hi = __hip_atomic_load(&crec64[idx * 2 + 1], __ATOMIC_RELAXED, __HIP_MEMORY_SCOPE_AGENT);
                unsigned int meta = __hip_atomic_load(&cmeta[idx], __ATOMIC_RELAXED, __HIP_MEMORY_SCOPE_AGENT);
                float xj = __uint_as_float((unsigned int)lo);
                float yj = __uint_as_float((unsigned int)(lo >> 32));
                float zj = __uint_as_float((unsigned int)hi);
                float rj = __uint_as_float((unsigned int)(hi >> 32));
                float dx = pi.x - xj;
                float dy = pi.y - yj;
                float dz = pi.z - zj;
                float dr2 = fmaf(dx, dx, fmaf(dy, dy, dz * dz));
                if (dr2 < RC2 && (int)(meta >> 2) != i) {
                    int sj = (int)(meta & 3u);
                    float e = ls[(si << 2) | sj];
                    float a = ls[16 + ((si << 2) | sj)];
                    float dr = sqrtf(dr2);
                    float ex = __expf(-a * (dr - (pi.w + rj)));
                    float om = 1.0f - ex;
                    float u = fmaf(e * om, om, -e);          // eps*(1-ex)^2 - eps
                    float smooth = 1.0f;
                    if (dr2 >= RO2) {
                        float d = RC2 - dr2;
                        smooth = d * d * fmaf(2.0f, dr2, C1) * INV_D;
                    }
                    acc += u * smooth;
                }
            }
        }
    }
    acc *= 0.5f;                            // ordered pairs counted twice

    // wave(64) shuffle reduction -> LDS -> block sum
#pragma unroll
    for (int off = 32; off > 0; off >>= 1) acc += __shfl_down(acc, off, 64);
    if ((t & 63) == 0) red[t >> 6] = acc;
    __syncthreads();

    // proven poison-counter fused finalize
    int lastv = 0;
    if (t == 0) {
        atomicAdd(&acc64[b & 63], red[0] + red[1] + red[2] + red[3]);
        __threadfence();
        unsigned int old = atomicAdd(cnt, 1u);               // cnt starts at poison
        lastv = (old == POISON_U + (NBLOCKS - 1)) ? 1 : 0;
    }
    if (t < 64) {
        int lastw = __shfl(lastv, 0, 64);
        if (lastw) {
            __threadfence();
            float v = atomicAdd(&acc64[t], 0.0f) - __uint_as_float(POISON_U);
#pragma unroll
            for (int off = 32; off > 0; off >>= 1) v += __shfl_down(v, off, 64);
            if (t == 0) {
                if (bf) ((__hip_bfloat16*)out)[0] = __float2bfloat16(v);
                else    ((float*)out)[0] = v;
            }
        }
    }
}

extern "C" void kernel_launch(void* const* d_in, const int* in_sizes, int n_in,
                              void* d_out, int out_size, void* d_ws, size_t ws_size,
                              hipStream_t stream)
{
    const void* eps = nullptr; const void* alp = nullptr;
    const void* ct = nullptr;  const void* rad = nullptr; const void* pos = nullptr;
    int nsmall = 0;
    for (int k = 0; k < n_in; ++k) {
        int s = in_sizes[k];
        if (s == NCT * NCT)        { if (nsmall++ == 0) eps = d_in[k]; else alp = d_in[k]; }
        else if (s == NPART * NCT) ct  = d_in[k];
        else if (s == NPART)       rad = d_in[k];
        else if (s == NPART * 3)   pos = d_in[k];
    }
    if (!eps || !alp || !ct || !rad || !pos) {
        eps = d_in[0]; alp = d_in[1]; ct = d_in[2]; rad = d_in[3]; pos = d_in[4];
    }

    char* ws = (char*)d_ws;
    float*              acc64  = (float*)(ws + 0);
    unsigned int*       cnt    = (unsigned int*)(ws + 256);
    unsigned int*       bar    = (unsigned int*)(ws + 260);
    unsigned int*       count  = (unsigned int*)(ws + 512);
    unsigned long long* crec64 = (unsigned long long*)(ws + 32768);
    unsigned int*       cmeta  = (unsigned int*)(ws + 1568768);

    morse_fused_kernel<<<NBLOCKS, TPB, 0, stream>>>(eps, alp, ct, rad, pos,
                                                    acc64, cnt, bar, count, crec64, cmeta,
                                                    d_out);
}

// Round 11
// 82.559 us; speedup vs baseline: 1.6035x; 1.6035x over previous
//
#include <hip/hip_runtime.h>
#include <hip/hip_bf16.h>

#define NPART 8192
#define NCT 4
#define CDIM 20
#define NCELL (CDIM * CDIM * CDIM)          // 8000 cells, cell edge = cutoff = 2.0
#define CAP 12                              // max particles/cell (lambda~1.02)
#define POISON_U 0xAAAAAAAAu
#define PAIR_TPB 256
#define PAIR_BLOCKS (NPART * 27 / PAIR_TPB) // 864, exact

// ws layout (bytes):
//   0        float  acc64[64]        poison-biased partial sums (proven finalize)
//   256      uint   cnt              finalize counter (poisoned)
//   512      float4 upos4[8192]      packed {x,y,z, rad|i|s|valid}      (131072 B)
//   135168   float4 bins[8000*12]    cell records, poison = empty slot  (1536000 B)
//   1703936  uint   count[8000]      poison-biased slot counters (decode only)

__device__ __forceinline__ float loadf(const void* p, int idx, bool bf) {
    if (bf) {
        unsigned int u = ((const unsigned short*)p)[idx];
        return __uint_as_float(u << 16);
    }
    return ((const float*)p)[idx];
}

__device__ __forceinline__ int spec_of(const void* ct, int i, bool bf) {
    int s = -1;
#pragma unroll
    for (int c = 0; c < NCT; ++c)
        if (loadf(ct, i * NCT + c, bf) > 0.5f) s = c;
    return s;
}

__device__ __forceinline__ int cell_coord(float v) {
    return min(CDIM - 1, max(0, (int)(v * 0.5f)));
}

// record w field: [31:16]=rad bf16 bits, [15:3]=particle index, [2:1]=species, [0]=valid
__device__ __forceinline__ unsigned int pack_w(float rad, int i, int s) {
    return (__float_as_uint(rad) & 0xFFFF0000u) | ((unsigned int)i << 3)
           | ((unsigned int)s << 1) | 1u;
}

// K1: decode -> packed upos4 + direct scatter into poison-marked cell bins
__global__ __launch_bounds__(64) void decode_kernel(const void* __restrict__ ct,
                                                    const void* __restrict__ rad,
                                                    const void* __restrict__ pos,
                                                    float4* __restrict__ upos4,
                                                    float4* __restrict__ bins,
                                                    unsigned int* __restrict__ count)
{
    const int t = threadIdx.x;
    unsigned int wdet = ((const unsigned int*)ct)[t & 63];
    const bool bf = (__ballot((wdet & 0xFFFFu) != 0) != 0ull);

    const int i = blockIdx.x * 64 + t;
    float4 p;
    p.x = loadf(pos, i * 3 + 0, bf);
    p.y = loadf(pos, i * 3 + 1, bf);
    p.z = loadf(pos, i * 3 + 2, bf);
    float r = loadf(rad, i, bf);
    int s = spec_of(ct, i, bf);

    if (s >= 0) {
        p.w = __uint_as_float(pack_w(r, i, s));
        int c = (cell_coord(p.z) * CDIM + cell_coord(p.y)) * CDIM + cell_coord(p.x);
        unsigned int slot = atomicAdd(&count[c], 1u) - POISON_U;  // counters start at poison
        if (slot < CAP) bins[c * CAP + (int)slot] = p;
    } else {
        p.w = __uint_as_float(0u);          // dead particle: valid bit clear
    }
    upos4[i] = p;
}

// K2: thread = (particle i, neighbor-cell k in 0..26); one 16B load per candidate
__global__ __launch_bounds__(PAIR_TPB) void pair_kernel(const void* __restrict__ eps,
                                                        const void* __restrict__ alp,
                                                        const void* __restrict__ ct,
                                                        const float4* __restrict__ upos4,
                                                        const float4* __restrict__ bins,
                                                        float* __restrict__ acc64,
                                                        unsigned int* __restrict__ cnt,
                                                        void* __restrict__ out)
{
    __shared__ float ls[32];
    __shared__ float red[PAIR_TPB / 64];
    const int t = threadIdx.x;

    unsigned int wdet = ((const unsigned int*)ct)[t & 63];
    const bool bf = (__ballot((wdet & 0xFFFFu) != 0) != 0ull);

    // species tables in LDS: symmetrize + sigmoid*vmax + vmin (R7-proven)
    if (t < 16) {
        int a = t >> 2, c = t & 3;
        float me = (a == c) ? loadf(eps, a * NCT + a, bf)
                            : 0.5f * (loadf(eps, a * NCT + c, bf) + loadf(eps, c * NCT + a, bf));
        float ma = (a == c) ? loadf(alp, a * NCT + a, bf)
                            : 0.5f * (loadf(alp, a * NCT + c, bf) + loadf(alp, c * NCT + a, bf));
        ls[t]      = 5.0f / (1.0f + __expf(-me)) + 1.0f;   // EPS range
        ls[16 + t] = 3.0f / (1.0f + __expf(-ma)) + 1.0f;   // ALPHA range
    }
    __syncthreads();

    const int gtid = blockIdx.x * PAIR_TPB + t;
    const int i = gtid / 27;                 // magic-mul
    const int k = gtid - i * 27;

    constexpr float RC2 = 4.0f;              // R_CUTOFF^2
    constexpr float RO2 = 1.7f * 1.7f;       // R_ONSET^2
    constexpr float C1  = RC2 - 3.0f * RO2;
    const float INV_D = 1.0f / ((RC2 - RO2) * (RC2 - RO2) * (RC2 - RO2));

    float acc = 0.0f;
    const float4 pi = upos4[i];              // ~2-3 distinct addrs/wave -> broadcast
    const unsigned int wi = __float_as_uint(pi.w);

    if (wi & 1u) {                           // alive
        const int si = (int)((wi >> 1) & 3u);
        const float ri = __uint_as_float(wi & 0xFFFF0000u);
        const int xx = cell_coord(pi.x) + (k % 3) - 1;
        const int yy = cell_coord(pi.y) + ((k / 3) % 3) - 1;
        const int zz = cell_coord(pi.z) + (k / 9) - 1;
        if (xx >= 0 && xx < CDIM && yy >= 0 && yy < CDIM && zz >= 0 && zz < CDIM) {
            const int c = (zz * CDIM + yy) * CDIM + xx;
#pragma unroll 2
            for (int ss = 0; ss < CAP; ++ss) {
                float4 pj = bins[c * CAP + ss];          // ONE 16B load per candidate
                unsigned int wj = __float_as_uint(pj.w);
                if (!(wj & 1u)) break;                   // poison slot -> end of cell
                int j = (int)((wj >> 3) & 0x1FFFu);
                float dx = pi.x - pj.x;
                float dy = pi.y - pj.y;
                float dz = pi.z - pj.z;
                float dr2 = fmaf(dx, dx, fmaf(dy, dy, dz * dz));
                if (dr2 < RC2 && j != i) {
                    int sj = (int)((wj >> 1) & 3u);
                    float rj = __uint_as_float(wj & 0xFFFF0000u);
                    float e = ls[(si << 2) | sj];
                    float a = ls[16 + ((si << 2) | sj)];
                    float dr = sqrtf(dr2);
                    float ex = __expf(-a * (dr - (ri + rj)));
                    float om = 1.0f - ex;
                    float u = fmaf(e * om, om, -e);      // eps*(1-ex)^2 - eps
                    float smooth = 1.0f;
                    if (dr2 >= RO2) {
                        float d = RC2 - dr2;
                        smooth = d * d * fmaf(2.0f, dr2, C1) * INV_D;
                    }
                    acc += u * smooth;
                }
            }
        }
    }
    acc *= 0.5f;                             // ordered pairs counted twice

    // wave(64) shuffle reduction -> LDS -> block sum
#pragma unroll
    for (int off = 32; off > 0; off >>= 1) acc += __shfl_down(acc, off, 64);
    if ((t & 63) == 0) red[t >> 6] = acc;
    __syncthreads();

    // proven poison-counter fused finalize
    int lastv = 0;
    if (t == 0) {
        atomicAdd(&acc64[blockIdx.x & 63], red[0] + red[1] + red[2] + red[3]);
        __threadfence();
        unsigned int old = atomicAdd(cnt, 1u);           // cnt starts at poison
        lastv = (old == POISON_U + (PAIR_BLOCKS - 1)) ? 1 : 0;
    }
    if (t < 64) {
        int lastw = __shfl(lastv, 0, 64);
        if (lastw) {
            __threadfence();
            float v = atomicAdd(&acc64[t], 0.0f) - __uint_as_float(POISON_U);
#pragma unroll
            for (int off = 32; off > 0; off >>= 1) v += __shfl_down(v, off, 64);
            if (t == 0) {
                if (bf) ((__hip_bfloat16*)out)[0] = __float2bfloat16(v);
                else    ((float*)out)[0] = v;
            }
        }
    }
}

extern "C" void kernel_launch(void* const* d_in, const int* in_sizes, int n_in,
                              void* d_out, int out_size, void* d_ws, size_t ws_size,
                              hipStream_t stream)
{
    const void* eps = nullptr; const void* alp = nullptr;
    const void* ct = nullptr;  const void* rad = nullptr; const void* pos = nullptr;
    int nsmall = 0;
    for (int k = 0; k < n_in; ++k) {
        int s = in_sizes[k];
        if (s == NCT * NCT)        { if (nsmall++ == 0) eps = d_in[k]; else alp = d_in[k]; }
        else if (s == NPART * NCT) ct  = d_in[k];
        else if (s == NPART)       rad = d_in[k];
        else if (s == NPART * 3)   pos = d_in[k];
    }
    if (!eps || !alp || !ct || !rad || !pos) {
        eps = d_in[0]; alp = d_in[1]; ct = d_in[2]; rad = d_in[3]; pos = d_in[4];
    }

    char* ws = (char*)d_ws;
    float*        acc64 = (float*)(ws + 0);
    unsigned int* cnt   = (unsigned int*)(ws + 256);
    float4*       upos4 = (float4*)(ws + 512);
    float4*       bins  = (float4*)(ws + 135168);
    unsigned int* count = (unsigned int*)(ws + 1703936);

    decode_kernel<<<NPART / 64, 64, 0, stream>>>(ct, rad, pos, upos4, bins, count);
    pair_kernel<<<PAIR_BLOCKS, PAIR_TPB, 0, stream>>>(eps, alp, ct, upos4, bins,
                                                      acc64, cnt, d_out);
}